// Round 3
// baseline (1624.306 us; speedup 1.0000x reference)
//
#include <hip/hip_runtime.h>
#include <cmath>

// PropConv: K=10 hop gated propagation on a fixed graph + output MLP.
// R3: 4-byte edge payload (src|etype<<16; gate via LDS table; src_norm folded
// into the stored h as g=h*srcn), deg builds only incnt (outcnt moved into
// scatter), hop gathers unrolled x8, MLP retiled to 8x4/thread all-float4.

#define NNODES 50000
#define NEDGES 1600000
#define DD 128
#define KHOPS 10
#define ALPHA 0.1f

// 8-entry gate table: gate MLP has only 8 distinct inputs (etypes).
__global__ void gate_kernel(const float* __restrict__ emb, const float* __restrict__ We1,
                            const float* __restrict__ be1, const float* __restrict__ We2,
                            const float* __restrict__ be2, float* __restrict__ gate) {
    int t = threadIdx.x;
    if (t >= 8) return;
    float acc2 = 0.0f;
    for (int j = 0; j < 32; j++) {
        float a = be1[j];
        for (int k = 0; k < DD; k++) a += emb[t * DD + k] * We1[k * 32 + j];
        float g = 0.5f * a * (1.0f + erff(a * 0.70710678118654752f));  // exact GELU
        acc2 += g * We2[j];
    }
    acc2 += be2[0];
    gate[t] = 1.0f + 1.0f / (1.0f + expf(-acc2));   // 1 + sigmoid
}

__global__ void deg_in_kernel(const int* __restrict__ dst, int* __restrict__ incnt, int E) {
    int e = blockIdx.x * blockDim.x + threadIdx.x;
    if (e < E) atomicAdd(&incnt[dst[e]], 1);
}

// Single-block exclusive scan of in-degree counts -> row_ptr.
__global__ __launch_bounds__(1024) void scan_kernel(const int* __restrict__ cnt,
                                                    int* __restrict__ row_ptr, int N, int E) {
    __shared__ int part[1024];
    int t = threadIdx.x;
    int chunk = (N + 1023) / 1024;
    int beg = t * chunk; if (beg > N) beg = N;
    int end = beg + chunk; if (end > N) end = N;
    int s = 0;
    for (int i = beg; i < end; i++) s += cnt[i];
    part[t] = s;
    __syncthreads();
    for (int off = 1; off < 1024; off <<= 1) {
        int v = 0;
        if (t >= off) v = part[t - off];
        __syncthreads();
        if (t >= off) part[t] += v;
        __syncthreads();
    }
    int excl = (t == 0) ? 0 : part[t - 1];
    for (int i = beg; i < end; i++) { row_ptr[i] = excl; excl += cnt[i]; }
    if (t == 0) row_ptr[N] = E;
}

// Bucket edges by dst. 4B payload: src (16b) | etype (<<16). Also builds outcnt.
__global__ void scatter_kernel(const int* __restrict__ src, const int* __restrict__ dst,
                               const int* __restrict__ ef, const int* __restrict__ row_ptr,
                               int* __restrict__ cursor, int* __restrict__ outcnt,
                               int* __restrict__ epay, int E) {
    int e = blockIdx.x * blockDim.x + threadIdx.x;
    if (e >= E) return;
    int d = dst[e];
    int s = src[e];
    int pos = row_ptr[d] + atomicAdd(&cursor[d], 1);
    epay[pos] = s | (ef[e] << 16);
    atomicAdd(&outcnt[s], 1);
}

// g0 = feat * src_norm (src_norm folded into the stored state each hop).
__global__ void scale_kernel(const float* __restrict__ feat, const int* __restrict__ outcnt,
                             float* __restrict__ g0, int N) {
    int i = blockIdx.x * blockDim.x + threadIdx.x;   // one float4 per thread
    if (i >= N * 32) return;
    int row = i >> 5;
    int oc = outcnt[row]; if (oc < 1) oc = 1;
    float sn = rsqrtf((float)oc);
    float4 v = ((const float4*)feat)[i];
    v.x *= sn; v.y *= sn; v.z *= sn; v.w *= sn;
    ((float4*)g0)[i] = v;
}

// Half-wave (32 lanes) per dst node; lane holds float4 of the 512B row.
// Edge payloads loaded coalesced in chunks of 32, broadcast via __shfl;
// gate looked up from LDS (same-address broadcast). x8 unroll -> 8 gathers
// in flight per lane. Epilogue: h = .9*dstn*agg + .1*feat0; stores h*srcn
// (pre-scaled for next hop) except on the last hop, which stores h.
__global__ __launch_bounds__(256) void hop_kernel(const float* __restrict__ g_in,
                                                  const float* __restrict__ feat0,
                                                  const int* __restrict__ incnt,
                                                  const int* __restrict__ outcnt,
                                                  const float* __restrict__ gate_g,
                                                  const int* __restrict__ row_ptr,
                                                  const int* __restrict__ epay,
                                                  float* __restrict__ g_out, int N, int last) {
    __shared__ float gateL[8];
    if (threadIdx.x < 8) gateL[threadIdx.x] = gate_g[threadIdx.x];
    __syncthreads();
    int half = threadIdx.x >> 5;     // 0..7
    int lane = threadIdx.x & 31;
    int node = blockIdx.x * 8 + half;
    if (node >= N) return;
    int beg = row_ptr[node], end = row_ptr[node + 1];
    int col = lane * 4;
    float ax = 0.f, ay = 0.f, az = 0.f, aw = 0.f;
    for (int base = beg; base < end; base += 32) {
        int n = end - base; if (n > 32) n = 32;
        int p = 0;
        if (lane < n) p = epay[base + lane];
        int j = 0;
        for (; j + 8 <= n; j += 8) {
            int pj[8];
#pragma unroll
            for (int u = 0; u < 8; u++) pj[u] = __shfl(p, j + u, 32);
            float4 v[8];
#pragma unroll
            for (int u = 0; u < 8; u++)
                v[u] = *(const float4*)(g_in + (size_t)(pj[u] & 0xFFFF) * DD + col);
#pragma unroll
            for (int u = 0; u < 8; u++) {
                float c = gateL[(unsigned)pj[u] >> 16];
                ax += c * v[u].x; ay += c * v[u].y; az += c * v[u].z; aw += c * v[u].w;
            }
        }
        for (; j < n; j++) {
            int pj = __shfl(p, j, 32);
            float c = gateL[(unsigned)pj >> 16];
            float4 v = *(const float4*)(g_in + (size_t)(pj & 0xFFFF) * DD + col);
            ax += c * v.x; ay += c * v.y; az += c * v.z; aw += c * v.w;
        }
    }
    int ic = incnt[node]; if (ic < 1) ic = 1;
    float dn = rsqrtf((float)ic) * (1.0f - ALPHA);
    float4 fv = *(const float4*)(feat0 + (size_t)node * DD + col);
    float hx = dn * ax + ALPHA * fv.x;
    float hy = dn * ay + ALPHA * fv.y;
    float hz = dn * az + ALPHA * fv.z;
    float hw = dn * aw + ALPHA * fv.w;
    float sc = 1.0f;
    if (!last) {
        int oc = outcnt[node]; if (oc < 1) oc = 1;
        sc = rsqrtf((float)oc);
    }
    float4 o; o.x = hx * sc; o.y = hy * sc; o.z = hz * sc; o.w = hw * sc;
    *(float4*)(g_out + (size_t)node * DD + col) = o;
}

// [N,128]@[128,128] GEMM, f32 vector ALU (no f32 MFMA on CDNA4).
// 64-row tile; thread computes 8 rows x 4 cols; ins reads are lane-uniform
// (free LDS broadcast), W reads are b128 full-BW. VALU-bound by design.
__global__ __launch_bounds__(256) void mlp_kernel(const float* __restrict__ in,
                                                  const float* __restrict__ W,
                                                  const float* __restrict__ bias,
                                                  float* __restrict__ out, int N, int do_gelu) {
    __shared__ float ins[64 * DD];   // 32 KB
    __shared__ float Wt[64 * DD];    // 32 KB
    int tid = threadIdx.x;
    int row0 = blockIdx.x * 64;
    int nrows = N - row0; if (nrows > 64) nrows = 64;
    for (int i = tid; i < nrows * 32; i += 256)
        ((float4*)ins)[i] = ((const float4*)(in + (size_t)row0 * DD))[i];

    int jc = (tid & 31) * 4;
    int rg = (tid >> 5) * 8;
    float acc[8][4];
#pragma unroll
    for (int r = 0; r < 8; r++)
#pragma unroll
        for (int c = 0; c < 4; c++) acc[r][c] = 0.0f;

    for (int k0 = 0; k0 < DD; k0 += 64) {
        __syncthreads();
        for (int i = tid; i < 64 * 32; i += 256)
            ((float4*)Wt)[i] = ((const float4*)(W + (size_t)k0 * DD))[i];
        __syncthreads();
#pragma unroll 2
        for (int k = 0; k < 64; k += 4) {
            float4 wv[4];
#pragma unroll
            for (int i = 0; i < 4; i++) wv[i] = *(const float4*)&Wt[(k + i) * DD + jc];
#pragma unroll
            for (int r = 0; r < 8; r++) {
                float4 a = *(const float4*)&ins[(rg + r) * DD + k0 + k];
                acc[r][0] += a.x * wv[0].x + a.y * wv[1].x + a.z * wv[2].x + a.w * wv[3].x;
                acc[r][1] += a.x * wv[0].y + a.y * wv[1].y + a.z * wv[2].y + a.w * wv[3].y;
                acc[r][2] += a.x * wv[0].z + a.y * wv[1].z + a.z * wv[2].z + a.w * wv[3].z;
                acc[r][3] += a.x * wv[0].w + a.y * wv[1].w + a.z * wv[2].w + a.w * wv[3].w;
            }
        }
    }
    float4 bv = *(const float4*)&bias[jc];
#pragma unroll
    for (int r = 0; r < 8; r++) {
        int row = row0 + rg + r;
        if (row >= N) continue;
        float4 v;
        v.x = acc[r][0] + bv.x; v.y = acc[r][1] + bv.y;
        v.z = acc[r][2] + bv.z; v.w = acc[r][3] + bv.w;
        if (do_gelu) {
            v.x = 0.5f * v.x * (1.0f + erff(v.x * 0.70710678118654752f));
            v.y = 0.5f * v.y * (1.0f + erff(v.y * 0.70710678118654752f));
            v.z = 0.5f * v.z * (1.0f + erff(v.z * 0.70710678118654752f));
            v.w = 0.5f * v.w * (1.0f + erff(v.w * 0.70710678118654752f));
        }
        *(float4*)(out + (size_t)row * DD + jc) = v;
    }
}

extern "C" void kernel_launch(void* const* d_in, const int* in_sizes, int n_in,
                              void* d_out, int out_size, void* d_ws, size_t ws_size,
                              hipStream_t stream) {
    const float* feat = (const float*)d_in[0];
    const int*   e_feat = (const int*)d_in[1];
    const int*   src = (const int*)d_in[2];
    const int*   dst = (const int*)d_in[3];
    const float* emb = (const float*)d_in[4];
    const float* We1 = (const float*)d_in[5];
    const float* be1 = (const float*)d_in[6];
    const float* We2 = (const float*)d_in[7];
    const float* be2 = (const float*)d_in[8];
    const float* W1  = (const float*)d_in[9];
    const float* b1  = (const float*)d_in[10];
    const float* W2  = (const float*)d_in[11];
    const float* b2  = (const float*)d_in[12];
    float* out = (float*)d_out;

    const int N = NNODES, E = NEDGES;
    char* ws = (char*)d_ws;
    size_t off = 0;
    float* ga = (float*)(ws + off);      off += (size_t)N * DD * 4;   // 25.6 MB
    float* gb = (float*)(ws + off);      off += (size_t)N * DD * 4;   // 25.6 MB
    int*   epay = (int*)(ws + off);      off += (size_t)E * 4;        // 6.4 MB
    int*   row_ptr = (int*)(ws + off);   off += (size_t)(N + 1) * 4;
    int*   cnts = (int*)(ws + off);      off += (size_t)3 * N * 4;    // incnt|outcnt|cursor
    float* gate = (float*)(ws + off);    off += 64;
    int* incnt  = cnts;
    int* outcnt = cnts + N;
    int* cursor = cnts + 2 * N;

    hipMemsetAsync(cnts, 0, (size_t)3 * N * 4, stream);
    gate_kernel<<<1, 64, 0, stream>>>(emb, We1, be1, We2, be2, gate);
    deg_in_kernel<<<E / 256, 256, 0, stream>>>(dst, incnt, E);
    scan_kernel<<<1, 1024, 0, stream>>>(incnt, row_ptr, N, E);
    scatter_kernel<<<E / 256, 256, 0, stream>>>(src, dst, e_feat, row_ptr,
                                                cursor, outcnt, epay, E);
    scale_kernel<<<(N * 32 + 255) / 256, 256, 0, stream>>>(feat, outcnt, ga, N);

    const float* gin = ga;
    float* gout = gb;
    for (int k = 0; k < KHOPS; k++) {
        hop_kernel<<<(N + 7) / 8, 256, 0, stream>>>(gin, feat, incnt, outcnt, gate,
                                                    row_ptr, epay, gout, N, k == KHOPS - 1);
        gin = gout;
        gout = (gout == ga) ? gb : ga;
    }
    // gin = final h (ga after 10 hops); gout = free buffer (gb) -> hidden.
    float* hidden = gout;
    mlp_kernel<<<(N + 63) / 64, 256, 0, stream>>>(gin, W1, b1, hidden, N, 1);
    mlp_kernel<<<(N + 63) / 64, 256, 0, stream>>>(hidden, W2, b2, out, N, 0);
}